// Round 5
// baseline (1253.437 us; speedup 1.0000x reference)
//
#include <hip/hip_runtime.h>

#define BB 16
#define SS 1024
#define NPAD 1024      // padded matrix dim: real 1023 + identity pad row/col
#define NBLK 128
#define NSTEP 8        // NPAD / NBLK
#define TILEPK 32768   // packed bf16 tile: 4 ksteps x (4096 hi + 4096 lo)

typedef __attribute__((ext_vector_type(8))) __bf16 bf16x8;
typedef __attribute__((ext_vector_type(4))) float f32x4;

// ---------- helpers ----------
__device__ __forceinline__ unsigned int enc_f32(float f) {
  unsigned int u = __float_as_uint(f);
  return (u & 0x80000000u) ? ~u : (u | 0x80000000u);
}
__device__ __forceinline__ float dec_key(unsigned int k) {
  unsigned int u = (k & 0x80000000u) ? (k & 0x7fffffffu) : ~k;
  return __uint_as_float(u);
}
// async global->LDS, 16B per lane; LDS dest = wave-uniform base + lane*16
__device__ __forceinline__ void gload16(const __bf16* g, __bf16* l) {
  __builtin_amdgcn_global_load_lds(
      (const __attribute__((address_space(1))) void*)g,
      (__attribute__((address_space(3))) void*)l, 16, 0, 0);
}

// ---------- K0: init max key ----------
__global__ void __launch_bounds__(64) kinit(unsigned long long* mk) { *mk = 0ull; }

// ---------- K1: global max + argmax of scores ----------
__global__ void __launch_bounds__(256) kmax(const float* __restrict__ sc,
                                            unsigned long long* __restrict__ mk) {
  __shared__ unsigned long long red[256];
  const long long n = (long long)BB * SS * SS;
  unsigned long long best = 0ull;
  for (long long i = (long long)blockIdx.x * 256 + threadIdx.x; i < n;
       i += (long long)gridDim.x * 256) {
    unsigned long long k = ((unsigned long long)enc_f32(sc[i]) << 32) | (unsigned int)i;
    if (k > best) best = k;
  }
  red[threadIdx.x] = best;
  __syncthreads();
  for (int s = 128; s > 0; s >>= 1) {
    if ((int)threadIdx.x < s) {
      unsigned long long o = red[threadIdx.x + s];
      if (o > red[threadIdx.x]) red[threadIdx.x] = o;
    }
    __syncthreads();
  }
  if (threadIdx.x == 0) atomicMax(mk, red[0]);
}

// ---------- K2: build padded Laplacian minor M ----------
__global__ void __launch_bounds__(256) kbuild(const float* __restrict__ sc,
                                              float* __restrict__ M,
                                              const unsigned long long* __restrict__ mk) {
  __shared__ float red[256];
  const int r = blockIdx.x;
  const int b = blockIdx.y;
  const int t = threadIdx.x;
  float* Mrow = M + ((size_t)b * NPAD + r) * NPAD;
  if (r == NPAD - 1) {
    for (int c = t; c < NPAD; c += 256) Mrow[c] = (c == NPAD - 1) ? 1.0f : 0.0f;
    return;
  }
  const float m = dec_key((unsigned int)(*mk >> 32));
  const int i = r + 1;
  const float* srow = sc + ((size_t)b * SS + i) * SS;
  float part = 0.f;
  for (int j = t; j < SS; j += 256) part += expf(srow[j] - m);
  red[t] = part;
  __syncthreads();
  for (int s = 128; s > 0; s >>= 1) {
    if (t < s) red[t] += red[t + s];
    __syncthreads();
  }
  const float rs = red[0];
  for (int c = t; c < NPAD; c += 256) {
    float v;
    if (c == NPAD - 1) v = 0.0f;
    else {
      v = -expf(srow[c + 1] - m);
      if (c == r) v += rs;
    }
    Mrow[c] = v;
  }
}

// ---------- prologue K3a+K3b (kb=0 only): pack column 0 + GJ(0) ----------
__global__ void __launch_bounds__(256) kcopydiag(const float* __restrict__ M,
                                                 __bf16* __restrict__ Tpk,
                                                 float* __restrict__ D,
                                                 __bf16* __restrict__ DA,
                                                 __bf16* __restrict__ DB, int kb) {
  const int x = blockIdx.x;
  const int t = threadIdx.x;
  if (x < NSTEP * BB) {
    const int rt = x >> 4, b = x & 15;
    const float* src = M + ((size_t)b * NPAD + rt * NBLK) * NPAD + kb * NBLK;
    __bf16* dst = Tpk + ((size_t)b * NSTEP + rt) * TILEPK;
#pragma unroll
    for (int itr = 0; itr < 8; ++itr) {
      const int gid = itr * 256 + t;
      const int m15 = gid & 15, q = (gid >> 4) & 3, R = (gid >> 6) & 7, ks = gid >> 9;
      const float* sp = src + (size_t)(R * 16 + m15) * NPAD + ks * 32 + q * 8;
      float f[8];
      *(float4*)(f + 0) = *(const float4*)(sp);
      *(float4*)(f + 4) = *(const float4*)(sp + 4);
      bf16x8 hv, lv;
#pragma unroll
      for (int j = 0; j < 8; ++j) {
        const float xv = f[j];
        const __bf16 h = (__bf16)xv;
        hv[j] = h;
        lv[j] = (__bf16)(xv - (float)h);
      }
      const int fi = ((R * 4 + q) * 16 + m15) * 8;
      *(bf16x8*)&dst[(size_t)ks * 8192 + fi] = hv;
      *(bf16x8*)&dst[(size_t)ks * 8192 + 4096 + fi] = lv;
    }
    return;
  }
  __shared__ float ds16[16][16];
  __shared__ float pinv16[16][18];
  __shared__ float rowp[16][128];
  __shared__ float rext[16][128];
  __shared__ float colp[128][20];
  __shared__ __bf16 Bsh[128][130];
  const int b = x - NSTEP * BB;
  const int tx = t & 15, ty = t >> 4;
  const int l = t & 63;
  const int lrow = l & 15, lcg = l >> 4;
  const float* src = M + ((size_t)b * NPAD + kb * NBLK) * NPAD + kb * NBLK;
  float r[8][8];
#pragma unroll
  for (int ii = 0; ii < 8; ++ii) {
    const float* sp = src + (size_t)(ty + 16 * ii) * NPAD + 8 * tx;
    *(float4*)&r[ii][0] = *(const float4*)(sp);
    *(float4*)&r[ii][4] = *(const float4*)(sp + 4);
  }

  for (int g = 0; g < 8; ++g) {
    const bool own_pc = ((tx >> 1) == g);
#pragma unroll
    for (int ii = 0; ii < 8; ++ii) {
      if (ii == g) {
        *(float4*)&rowp[ty][8 * tx] = *(const float4*)&r[ii][0];
        *(float4*)&rowp[ty][8 * tx + 4] = *(const float4*)&r[ii][4];
        if (own_pc) {
          *(float4*)&ds16[ty][8 * (tx & 1)] = *(const float4*)&r[ii][0];
          *(float4*)&ds16[ty][8 * (tx & 1) + 4] = *(const float4*)&r[ii][4];
        }
      }
      if (own_pc) {
        *(float4*)&colp[ty + 16 * ii][8 * (tx & 1)] = *(const float4*)&r[ii][0];
        *(float4*)&colp[ty + 16 * ii][8 * (tx & 1) + 4] = *(const float4*)&r[ii][4];
      }
    }
    __syncthreads();
    float dd[4];
    {
      const f32x4 dv = *(const f32x4*)&ds16[lrow][4 * lcg];
      dd[0] = dv[0]; dd[1] = dv[1]; dd[2] = dv[2]; dd[3] = dv[3];
    }
#pragma unroll
    for (int k = 0; k < 16; ++k) {
      const int pcg = k >> 2, pr = k & 3;
      const float pv = __shfl(dd[pr], k + 16 * pcg);
      const float pinv = __builtin_amdgcn_rcpf(pv);
      const float ck = __shfl(dd[pr], lrow + 16 * pcg);
      float rk[4];
#pragma unroll
      for (int c = 0; c < 4; ++c) rk[c] = __shfl(dd[c], k + 16 * lcg);
      const bool isp = (lrow == k);
      const float cp = ck * pinv;
#pragma unroll
      for (int c = 0; c < 4; ++c) {
        const bool zc = (lcg == pcg) && (c == pr);
        const float upd = (zc ? 0.0f : dd[c]) - cp * (zc ? 1.0f : rk[c]);
        const float prw = zc ? pinv : dd[c] * pinv;
        dd[c] = isp ? prw : upd;
      }
    }
#pragma unroll
    for (int c = 0; c < 4; ++c) pinv16[lrow][4 * lcg + c] = dd[c];
    __syncthreads();
    float pvr[16];
#pragma unroll
    for (int a = 0; a < 16; ++a) pvr[a] = pinv16[ty][a];
    float Rv[8];
#pragma unroll
    for (int jj = 0; jj < 8; ++jj) Rv[jj] = 0.0f;
#pragma unroll
    for (int a = 0; a < 16; ++a) {
      const float pa = pvr[a];
      const f32x4 q0 = *(const f32x4*)&rowp[a][8 * tx];
      const f32x4 q1 = *(const f32x4*)&rowp[a][8 * tx + 4];
      Rv[0] += pa * q0[0]; Rv[1] += pa * q0[1]; Rv[2] += pa * q0[2]; Rv[3] += pa * q0[3];
      Rv[4] += pa * q1[0]; Rv[5] += pa * q1[1]; Rv[6] += pa * q1[2]; Rv[7] += pa * q1[3];
    }
    if (own_pc) {
#pragma unroll
      for (int jj = 0; jj < 8; ++jj) Rv[jj] = pinv16[ty][8 * (tx & 1) + jj];
    }
    {
      float4 w0 = make_float4(Rv[0], Rv[1], Rv[2], Rv[3]);
      float4 w1 = make_float4(Rv[4], Rv[5], Rv[6], Rv[7]);
      *(float4*)&rext[ty][8 * tx] = w0;
      *(float4*)&rext[ty][8 * tx + 4] = w1;
    }
    __syncthreads();
    if (own_pc) {
#pragma unroll
      for (int ii = 0; ii < 8; ++ii)
#pragma unroll
        for (int jj = 0; jj < 8; ++jj) r[ii][jj] = 0.0f;
    }
#pragma unroll
    for (int a0 = 0; a0 < 16; a0 += 4) {
      float ca[8][4];
#pragma unroll
      for (int ii = 0; ii < 8; ++ii)
        *(float4*)&ca[ii][0] = *(const float4*)&colp[ty + 16 * ii][a0];
#pragma unroll
      for (int ac = 0; ac < 4; ++ac) {
        const f32x4 ra0 = *(const f32x4*)&rext[a0 + ac][8 * tx];
        const f32x4 ra1 = *(const f32x4*)&rext[a0 + ac][8 * tx + 4];
#pragma unroll
        for (int ii = 0; ii < 8; ++ii) {
          const float cv = ca[ii][ac];
          r[ii][0] -= cv * ra0[0]; r[ii][1] -= cv * ra0[1];
          r[ii][2] -= cv * ra0[2]; r[ii][3] -= cv * ra0[3];
          r[ii][4] -= cv * ra1[0]; r[ii][5] -= cv * ra1[1];
          r[ii][6] -= cv * ra1[2]; r[ii][7] -= cv * ra1[3];
        }
      }
    }
#pragma unroll
    for (int ii = 0; ii < 8; ++ii) {
      if (ii == g) {
        const f32x4 ra0 = *(const f32x4*)&rext[ty][8 * tx];
        const f32x4 ra1 = *(const f32x4*)&rext[ty][8 * tx + 4];
        r[ii][0] = ra0[0]; r[ii][1] = ra0[1]; r[ii][2] = ra0[2]; r[ii][3] = ra0[3];
        r[ii][4] = ra1[0]; r[ii][5] = ra1[1]; r[ii][6] = ra1[2]; r[ii][7] = ra1[3];
      }
    }
    __syncthreads();
  }
  float* dst = D + (size_t)b * NBLK * NBLK;
  __bf16* dA = DA + (size_t)b * TILEPK;
  __bf16* dB = DB + (size_t)b * TILEPK;
#pragma unroll
  for (int ii = 0; ii < 8; ++ii) {
    *(float4*)(dst + (size_t)(ty + 16 * ii) * NBLK + 8 * tx) = *(const float4*)&r[ii][0];
    *(float4*)(dst + (size_t)(ty + 16 * ii) * NBLK + 8 * tx + 4) = *(const float4*)&r[ii][4];
    bf16x8 hv;
#pragma unroll
    for (int jj = 0; jj < 8; ++jj) {
      const float xv = r[ii][jj];
      const __bf16 h = (__bf16)xv;
      hv[jj] = h;
    }
    const int fiA = ((ii * 4 + (tx & 3)) * 16 + ty) * 8;
    bf16x8 lv;
#pragma unroll
    for (int jj = 0; jj < 8; ++jj) lv[jj] = (__bf16)(r[ii][jj] - (float)hv[jj]);
    *(bf16x8*)&dA[(size_t)(tx >> 2) * 8192 + fiA] = hv;
    *(bf16x8*)&dA[(size_t)(tx >> 2) * 8192 + 4096 + fiA] = lv;
    *(bf16x8*)&Bsh[ty + 16 * ii][8 * tx] = hv;
  }
  __syncthreads();
#pragma unroll
  for (int g8 = 0; g8 < 8; ++g8) {
    const int gid = g8 * 256 + t;
    const int n15 = gid & 15, q = (gid >> 4) & 3, Ct = (gid >> 6) & 7, ks = gid >> 9;
    const int n = Ct * 16 + n15, k0 = ks * 32 + q * 8;
    bf16x8 v;
#pragma unroll
    for (int j = 0; j < 8; ++j) v[j] = Bsh[k0 + j][n];
    *(bf16x8*)&dB[(size_t)ks * 4096 + (size_t)gid * 8] = v;
  }
  __syncthreads();
#pragma unroll
  for (int ii = 0; ii < 8; ++ii) {
    bf16x8 lv;
#pragma unroll
    for (int jj = 0; jj < 8; ++jj) {
      const float xv = r[ii][jj];
      const __bf16 h = (__bf16)xv;
      lv[jj] = (__bf16)(xv - (float)h);
    }
    *(bf16x8*)&Bsh[ty + 16 * ii][8 * tx] = lv;
  }
  __syncthreads();
#pragma unroll
  for (int g8 = 0; g8 < 8; ++g8) {
    const int gid = g8 * 256 + t;
    const int n15 = gid & 15, q = (gid >> 4) & 3, Ct = (gid >> 6) & 7, ks = gid >> 9;
    const int n = Ct * 16 + n15, k0 = ks * 32 + q * 8;
    bf16x8 v;
#pragma unroll
    for (int j = 0; j < 8; ++j) v[j] = Bsh[k0 + j][n];
    *(bf16x8*)&dB[(size_t)ks * 4096 + (size_t)gid * 8 + 4096] = v;
  }
}

// ---------- packed-input MFMA accumulate into caller acc (smem-carved staging) ----------
__device__ __forceinline__ void gemm_acc(const __bf16* __restrict__ pA,
                                         const __bf16* __restrict__ pB,
                                         char* smem, f32x4 acc[4][4]) {
  const int t = threadIdx.x;
  const int l = t & 63, w = t >> 6;
  const int rbase = (w & 1) * 4, cbase = (w >> 1) * 4;
  __bf16* sAb[2] = {(__bf16*)smem, (__bf16*)(smem + 16384)};
  __bf16* sBb[2] = {(__bf16*)(smem + 32768), (__bf16*)(smem + 49152)};
  {
    const __bf16* gA = pA + (size_t)w * 2048 + l * 8;
    const __bf16* gB = pB + (size_t)w * 2048 + l * 8;
#pragma unroll
    for (int i = 0; i < 4; ++i) {
      gload16(gA + i * 512, sAb[0] + w * 2048 + i * 512);
      gload16(gB + i * 512, sBb[0] + w * 2048 + i * 512);
    }
  }
  __syncthreads();
#pragma unroll
  for (int ks = 0; ks < 4; ++ks) {
    const int buf = ks & 1;
    if (ks < 3) {
      const __bf16* gA = pA + (size_t)(ks + 1) * 8192 + w * 2048 + l * 8;
      const __bf16* gB = pB + (size_t)(ks + 1) * 8192 + w * 2048 + l * 8;
#pragma unroll
      for (int i = 0; i < 4; ++i) {
        gload16(gA + i * 512, sAb[buf ^ 1] + w * 2048 + i * 512);
        gload16(gB + i * 512, sBb[buf ^ 1] + w * 2048 + i * 512);
      }
    }
    bf16x8 a_h[4], a_l[4];
#pragma unroll
    for (int rt = 0; rt < 4; ++rt) {
      a_h[rt] = *(const bf16x8*)&sAb[buf][(size_t)((rbase + rt) * 64 + l) * 8];
      a_l[rt] = *(const bf16x8*)&sAb[buf][4096 + (size_t)((rbase + rt) * 64 + l) * 8];
    }
#pragma unroll
    for (int ct = 0; ct < 4; ++ct) {
      bf16x8 b_h = *(const bf16x8*)&sBb[buf][(size_t)((cbase + ct) * 64 + l) * 8];
      bf16x8 b_l = *(const bf16x8*)&sBb[buf][4096 + (size_t)((cbase + ct) * 64 + l) * 8];
#pragma unroll
      for (int rt = 0; rt < 4; ++rt) {
        acc[rt][ct] = __builtin_amdgcn_mfma_f32_16x16x32_bf16(a_h[rt], b_h, acc[rt][ct], 0, 0, 0);
        acc[rt][ct] = __builtin_amdgcn_mfma_f32_16x16x32_bf16(a_h[rt], b_l, acc[rt][ct], 0, 0, 0);
        acc[rt][ct] = __builtin_amdgcn_mfma_f32_16x16x32_bf16(a_l[rt], b_h, acc[rt][ct], 0, 0, 0);
      }
    }
    if (ks < 3) __syncthreads();
  }
}

// ---------- standalone packed GEMM (final kupdate): C = beta*C + alpha*A*B ----------
__device__ __forceinline__ void gemm_pp(const __bf16* __restrict__ pA,
                                        const __bf16* __restrict__ pB,
                                        float* __restrict__ C, int ldc,
                                        float alpha, float beta) {
  __shared__ __align__(16) char smem_pp[65536];
  const int t = threadIdx.x;
  const int l = t & 63, w = t >> 6;
  f32x4 acc[4][4];
#pragma unroll
  for (int i = 0; i < 4; i++)
#pragma unroll
    for (int j = 0; j < 4; j++) acc[i][j] = (f32x4){0.f, 0.f, 0.f, 0.f};
  gemm_acc(pA, pB, smem_pp, acc);
  const int row0 = (w & 1) * 64 + ((l >> 4) << 2);
  const int col0 = (w >> 1) * 64 + (l & 15);
  if (beta == 0.0f) {
#pragma unroll
    for (int rt = 0; rt < 4; ++rt)
#pragma unroll
      for (int ct = 0; ct < 4; ++ct)
#pragma unroll
        for (int r = 0; r < 4; ++r)
          C[(size_t)(row0 + rt * 16 + r) * ldc + col0 + ct * 16] = alpha * acc[rt][ct][r];
  } else {
#pragma unroll
    for (int rt = 0; rt < 4; ++rt)
#pragma unroll
      for (int ct = 0; ct < 4; ++ct)
#pragma unroll
        for (int r = 0; r < 4; ++r) {
          float* cp = C + (size_t)(row0 + rt * 16 + r) * ldc + col0 + ct * 16;
          *cp = beta * (*cp) + alpha * acc[rt][ct][r];
        }
  }
}

// ---------- K3c: pivot block-row scale: B' = Dinv * B ----------
__global__ void __launch_bounds__(256) kscale(float* __restrict__ M,
                                              const float* __restrict__ D,
                                              const __bf16* __restrict__ DA,
                                              __bf16* __restrict__ Rpk, int kb) {
  const int jt = blockIdx.x, b = blockIdx.y;
  float* Mb = M + (size_t)b * NPAD * NPAD;
  const int t = threadIdx.x;
  if (jt == kb) {
    const float* Dinv = D + (size_t)b * NBLK * NBLK;
    const int c = (t & 31) * 4, r0 = t >> 5;
    float* dst = Mb + (size_t)(kb * NBLK) * NPAD + kb * NBLK;
    for (int r = r0; r < NBLK; r += 8)
      *(float4*)(dst + (size_t)r * NPAD + c) = *(const float4*)(Dinv + r * NBLK + c);
    return;
  }
  __shared__ __bf16 sA[8192];
  __shared__ __bf16 Bh[4096], Bl[4096];
  __shared__ __bf16 Bsh[128][130];
  const int l = t & 63, w = t >> 6;
  const int ic = t & 127, kh = t >> 7;
  const int rbase = (w & 1) * 4, cbase = (w >> 1) * 4;
  const __bf16* pA = DA + (size_t)b * TILEPK;
  float* Btile = Mb + (size_t)(kb * NBLK) * NPAD + jt * NBLK;

  f32x4 acc[4][4];
#pragma unroll
  for (int i = 0; i < 4; i++)
#pragma unroll
    for (int j = 0; j < 4; j++) acc[i][j] = (f32x4){0.f, 0.f, 0.f, 0.f};

  for (int ks = 0; ks < 4; ++ks) {
    const __bf16* gA = pA + (size_t)ks * 8192 + w * 2048 + l * 8;
#pragma unroll
    for (int i = 0; i < 4; ++i) gload16(gA + i * 512, &sA[w * 2048 + i * 512]);
    {
      const float* bp = Btile + (size_t)(ks * 32 + kh * 16) * NPAD + ic;
      float f[16];
#pragma unroll
      for (int kk = 0; kk < 16; ++kk) f[kk] = bp[(size_t)kk * NPAD];
      const int base = ((ic >> 4) * 4 + kh * 2) * 16 + (ic & 15);
#pragma unroll
      for (int g = 0; g < 2; ++g) {
        bf16x8 hv, lv;
#pragma unroll
        for (int j = 0; j < 8; ++j) {
          const float xv = f[g * 8 + j];
          const __bf16 h = (__bf16)xv;
          hv[j] = h;
          lv[j] = (__bf16)(xv - (float)h);
        }
        *(bf16x8*)&Bh[(size_t)(base + g * 16) * 8] = hv;
        *(bf16x8*)&Bl[(size_t)(base + g * 16) * 8] = lv;
      }
    }
    __syncthreads();
    bf16x8 a_h[4], a_l[4];
#pragma unroll
    for (int rt = 0; rt < 4; ++rt) {
      a_h[rt] = *(const bf16x8*)&sA[(size_t)((rbase + rt) * 64 + l) * 8];
      a_l[rt] = *(const bf16x8*)&sA[4096 + (size_t)((rbase + rt) * 64 + l) * 8];
    }
#pragma unroll
    for (int ct = 0; ct < 4; ++ct) {
      bf16x8 b_h = *(const bf16x8*)&Bh[(size_t)((cbase + ct) * 64 + l) * 8];
      bf16x8 b_l = *(const bf16x8*)&Bl[(size_t)((cbase + ct) * 64 + l) * 8];
#pragma unroll
      for (int rt = 0; rt < 4; ++rt) {
        acc[rt][ct] = __builtin_amdgcn_mfma_f32_16x16x32_bf16(a_h[rt], b_h, acc[rt][ct], 0, 0, 0);
        acc[rt][ct] = __builtin_amdgcn_mfma_f32_16x16x32_bf16(a_h[rt], b_l, acc[rt][ct], 0, 0, 0);
        acc[rt][ct] = __builtin_amdgcn_mfma_f32_16x16x32_bf16(a_l[rt], b_h, acc[rt][ct], 0, 0, 0);
      }
    }
    __syncthreads();
  }
  __bf16* Rt = Rpk + ((size_t)b * NSTEP + jt) * TILEPK;
  const int row0 = (w & 1) * 64 + ((l >> 4) << 2);
  const int col0 = (w >> 1) * 64 + (l & 15);
#pragma unroll
  for (int rt = 0; rt < 4; ++rt)
#pragma unroll
    for (int ct = 0; ct < 4; ++ct)
#pragma unroll
      for (int rr = 0; rr < 4; ++rr) {
        const float v = acc[rt][ct][rr];
        const int row = row0 + rt * 16 + rr;
        const int col = col0 + ct * 16;
        Btile[(size_t)row * NPAD + col] = v;
        Bsh[row][col] = (__bf16)v;
      }
  __syncthreads();
#pragma unroll
  for (int g8 = 0; g8 < 8; ++g8) {
    const int gid = g8 * 256 + t;
    const int n15 = gid & 15, q = (gid >> 4) & 3, Ct = (gid >> 6) & 7, ks = gid >> 9;
    const int n = Ct * 16 + n15, k0 = ks * 32 + q * 8;
    bf16x8 v;
#pragma unroll
    for (int j = 0; j < 8; ++j) v[j] = Bsh[k0 + j][n];
    *(bf16x8*)&Rt[(size_t)ks * 4096 + (size_t)gid * 8] = v;
  }
  __syncthreads();
#pragma unroll
  for (int rt = 0; rt < 4; ++rt)
#pragma unroll
    for (int ct = 0; ct < 4; ++ct)
#pragma unroll
      for (int rr = 0; rr < 4; ++rr) {
        const float v = acc[rt][ct][rr];
        const int row = row0 + rt * 16 + rr;
        const int col = col0 + ct * 16;
        const __bf16 h = (__bf16)v;
        Bsh[row][col] = (__bf16)(v - (float)h);
      }
  __syncthreads();
#pragma unroll
  for (int g8 = 0; g8 < 8; ++g8) {
    const int gid = g8 * 256 + t;
    const int n15 = gid & 15, q = (gid >> 4) & 3, Ct = (gid >> 6) & 7, ks = gid >> 9;
    const int n = Ct * 16 + n15, k0 = ks * 32 + q * 8;
    bf16x8 v;
#pragma unroll
    for (int j = 0; j < 8; ++j) v[j] = Bsh[k0 + j][n];
    *(bf16x8*)&Rt[(size_t)ks * 4096 + (size_t)gid * 8 + 4096] = v;
  }
}

// ---------- fused step kernel: x<16 GJ(kb+1, self-update) | 16..144 pack col kb+1 |
//            x>=144 trailing update (it!=kb, jt!=kb+1) ----------
__global__ void __launch_bounds__(256, 2) kfused(
    float* __restrict__ M,
    const __bf16* __restrict__ Tcur, __bf16* __restrict__ Tnxt,
    const __bf16* __restrict__ Rpk, const __bf16* __restrict__ DBc,
    float* __restrict__ Dn, __bf16* __restrict__ DAn, __bf16* __restrict__ DBn,
    int kb) {
  __shared__ __align__(16) char smem[65536];
  const int x = blockIdx.x;
  const int t = threadIdx.x;
  const int l = t & 63, w = t >> 6;
  const int row0 = (w & 1) * 64 + ((l >> 4) << 2);
  const int col0 = (w >> 1) * 64 + (l & 15);
  const int kd = kb + 1;

  if (x >= 144) {
    // ---- trailing update ----
    const int idx = x - 144;
    const int b = idx & 15, rem = idx >> 4;  // 0..48
    const int jt7 = rem % 7, it7 = rem / 7;
    const int jt = jt7 + (jt7 >= kd);
    const int it = it7 + (it7 >= kb);
    f32x4 acc[4][4];
#pragma unroll
    for (int i = 0; i < 4; i++)
#pragma unroll
      for (int j = 0; j < 4; j++) acc[i][j] = (f32x4){0.f, 0.f, 0.f, 0.f};
    const __bf16* pA = Tcur + ((size_t)b * NSTEP + it) * TILEPK;
    const __bf16* pB = (jt == kb) ? (DBc + (size_t)b * TILEPK)
                                  : (Rpk + ((size_t)b * NSTEP + jt) * TILEPK);
    gemm_acc(pA, pB, smem, acc);
    float* C = M + ((size_t)b * NPAD + it * NBLK) * NPAD + jt * NBLK;
    if (jt == kb) {
#pragma unroll
      for (int pt = 0; pt < 4; ++pt)
#pragma unroll
        for (int ct = 0; ct < 4; ++ct)
#pragma unroll
          for (int rr = 0; rr < 4; ++rr)
            C[(size_t)(row0 + pt * 16 + rr) * NPAD + col0 + ct * 16] = -acc[pt][ct][rr];
    } else {
#pragma unroll
      for (int pt = 0; pt < 4; ++pt)
#pragma unroll
        for (int ct = 0; ct < 4; ++ct)
#pragma unroll
          for (int rr = 0; rr < 4; ++rr) {
            float* cp = C + (size_t)(row0 + pt * 16 + rr) * NPAD + col0 + ct * 16;
            *cp = *cp - acc[pt][ct][rr];
          }
    }
    return;
  }

  if (x >= 16) {
    // ---- self-updating pack of column kd into Tnxt (A-layout) ----
    const int p = x - 16;
    const int rt = p >> 4, b = p & 15;
    f32x4 acc[4][4];
#pragma unroll
    for (int i = 0; i < 4; i++)
#pragma unroll
      for (int j = 0; j < 4; j++) acc[i][j] = (f32x4){0.f, 0.f, 0.f, 0.f};
    if (rt != kb) {  // pivot row (rt==kb) gets no update
      gemm_acc(Tcur + ((size_t)b * NSTEP + rt) * TILEPK,
               Rpk + ((size_t)b * NSTEP + kd) * TILEPK, smem, acc);
    }
    const float* Csrc = M + ((size_t)b * NPAD + rt * NBLK) * NPAD + kd * NBLK;
    __bf16* dst = Tnxt + ((size_t)b * NSTEP + rt) * TILEPK;
    float Cv[4][4][4];
#pragma unroll
    for (int pt = 0; pt < 4; ++pt)
#pragma unroll
      for (int ct = 0; ct < 4; ++ct)
#pragma unroll
        for (int rr = 0; rr < 4; ++rr)
          Cv[pt][ct][rr] =
              Csrc[(size_t)(row0 + pt * 16 + rr) * NPAD + col0 + ct * 16] - acc[pt][ct][rr];
    __syncthreads();  // staging dead
    __bf16(*Bsh)[136] = (__bf16(*)[136])smem;
#pragma unroll
    for (int pt = 0; pt < 4; ++pt)
#pragma unroll
      for (int ct = 0; ct < 4; ++ct)
#pragma unroll
        for (int rr = 0; rr < 4; ++rr)
          Bsh[row0 + pt * 16 + rr][col0 + ct * 16] = (__bf16)Cv[pt][ct][rr];
    __syncthreads();
#pragma unroll
    for (int g8 = 0; g8 < 8; ++g8) {
      const int gid = g8 * 256 + t;
      const int m15 = gid & 15, q = (gid >> 4) & 3, R = (gid >> 6) & 7, ks = gid >> 9;
      bf16x8 v = *(const bf16x8*)&Bsh[R * 16 + m15][ks * 32 + q * 8];
      *(bf16x8*)&dst[(size_t)ks * 4096 + (size_t)gid * 8] = v;
    }
    __syncthreads();
#pragma unroll
    for (int pt = 0; pt < 4; ++pt)
#pragma unroll
      for (int ct = 0; ct < 4; ++ct)
#pragma unroll
        for (int rr = 0; rr < 4; ++rr) {
          const float v = Cv[pt][ct][rr];
          const __bf16 h = (__bf16)v;
          Bsh[row0 + pt * 16 + rr][col0 + ct * 16] = (__bf16)(v - (float)h);
        }
    __syncthreads();
#pragma unroll
    for (int g8 = 0; g8 < 8; ++g8) {
      const int gid = g8 * 256 + t;
      const int m15 = gid & 15, q = (gid >> 4) & 3, R = (gid >> 6) & 7, ks = gid >> 9;
      bf16x8 v = *(const bf16x8*)&Bsh[R * 16 + m15][ks * 32 + q * 8];
      *(bf16x8*)&dst[(size_t)ks * 4096 + (size_t)gid * 8 + 4096] = v;
    }
    return;
  }

  // ---- GJ(kd) with self-update: r = Mdiag - Tcur(kd)*Rpk(kd) ----
  const int b = x;
  const int tx = t & 15, ty = t >> 4;
  const int lrow = l & 15, lcg = l >> 4;
  f32x4 acc[4][4];
#pragma unroll
  for (int i = 0; i < 4; i++)
#pragma unroll
    for (int j = 0; j < 4; j++) acc[i][j] = (f32x4){0.f, 0.f, 0.f, 0.f};
  gemm_acc(Tcur + ((size_t)b * NSTEP + kd) * TILEPK,
           Rpk + ((size_t)b * NSTEP + kd) * TILEPK, smem, acc);
  __syncthreads();  // staging dead

  float(*rowp)[128] = (float(*)[128])(smem);
  float(*rext)[128] = (float(*)[128])(smem + 8192);
  float(*colp)[20] = (float(*)[20])(smem + 16384);
  float(*ds16)[16] = (float(*)[16])(smem + 26624);
  float(*pinv16)[18] = (float(*)[18])(smem + 27648);
  float(*Msh)[132] = (float(*)[132])(smem + 28800);
  __bf16(*Bsh)[136] = (__bf16(*)[136])(smem + 28800);  // aliases Msh, disjoint lifetime

  const float* src = M + ((size_t)b * NPAD + kd * NBLK) * NPAD + kd * NBLK;
  float r[8][8];
  // remap acc (MFMA layout) -> r (GJ layout) via 32-row LDS chunks, fused with M read
#pragma unroll
  for (int c = 0; c < 4; ++c) {
    if ((w & 1) == (c >> 1)) {
      const int rt0 = (c & 1) * 2;
#pragma unroll
      for (int r2 = 0; r2 < 2; ++r2)
#pragma unroll
        for (int ct = 0; ct < 4; ++ct)
#pragma unroll
          for (int rr = 0; rr < 4; ++rr)
            Msh[r2 * 16 + ((l >> 4) << 2) + rr][col0 + ct * 16] = acc[rt0 + r2][ct][rr];
    }
    __syncthreads();
#pragma unroll
    for (int i2 = 0; i2 < 2; ++i2) {
      const int ii = 2 * c + i2;
      const int lr = ty + 16 * i2;
      const float* sp = src + (size_t)(ty + 16 * ii) * NPAD + 8 * tx;
      const f32x4 a0 = *(const f32x4*)&Msh[lr][8 * tx];
      const f32x4 a1 = *(const f32x4*)&Msh[lr][8 * tx + 4];
      const float4 m0 = *(const float4*)sp;
      const float4 m1 = *(const float4*)(sp + 4);
      r[ii][0] = m0.x - a0[0]; r[ii][1] = m0.y - a0[1];
      r[ii][2] = m0.z - a0[2]; r[ii][3] = m0.w - a0[3];
      r[ii][4] = m1.x - a1[0]; r[ii][5] = m1.y - a1[1];
      r[ii][6] = m1.z - a1[2]; r[ii][7] = m1.w - a1[3];
    }
    __syncthreads();
  }

  for (int g = 0; g < 8; ++g) {
    const bool own_pc = ((tx >> 1) == g);
#pragma unroll
    for (int ii = 0; ii < 8; ++ii) {
      if (ii == g) {
        *(float4*)&rowp[ty][8 * tx] = *(const float4*)&r[ii][0];
        *(float4*)&rowp[ty][8 * tx + 4] = *(const float4*)&r[ii][4];
        if (own_pc) {
          *(float4*)&ds16[ty][8 * (tx & 1)] = *(const float4*)&r[ii][0];
          *(float4*)&ds16[ty][8 * (tx & 1) + 4] = *(const float4*)&r[ii][4];
        }
      }
      if (own_pc) {
        *(float4*)&colp[ty + 16 * ii][8 * (tx & 1)] = *(const float4*)&r[ii][0];
        *(float4*)&colp[ty + 16 * ii][8 * (tx & 1) + 4] = *(const float4*)&r[ii][4];
      }
    }
    __syncthreads();
    float dd[4];
    {
      const f32x4 dv = *(const f32x4*)&ds16[lrow][4 * lcg];
      dd[0] = dv[0]; dd[1] = dv[1]; dd[2] = dv[2]; dd[3] = dv[3];
    }
#pragma unroll
    for (int k = 0; k < 16; ++k) {
      const int pcg = k >> 2, pr = k & 3;
      const float pv = __shfl(dd[pr], k + 16 * pcg);
      const float pinv = __builtin_amdgcn_rcpf(pv);
      const float ck = __shfl(dd[pr], lrow + 16 * pcg);
      float rk[4];
#pragma unroll
      for (int c = 0; c < 4; ++c) rk[c] = __shfl(dd[c], k + 16 * lcg);
      const bool isp = (lrow == k);
      const float cp = ck * pinv;
#pragma unroll
      for (int c = 0; c < 4; ++c) {
        const bool zc = (lcg == pcg) && (c == pr);
        const float upd = (zc ? 0.0f : dd[c]) - cp * (zc ? 1.0f : rk[c]);
        const float prw = zc ? pinv : dd[c] * pinv;
        dd[c] = isp ? prw : upd;
      }
    }
#pragma unroll
    for (int c = 0; c < 4; ++c) pinv16[lrow][4 * lcg + c] = dd[c];
    __syncthreads();
    float pvr[16];
#pragma unroll
    for (int a = 0; a < 16; ++a) pvr[a] = pinv16[ty][a];
    float Rv[8];
#pragma unroll
    for (int jj = 0; jj < 8; ++jj) Rv[jj] = 0.0f;
#pragma unroll
    for (int a = 0; a < 16; ++a) {
      const float pa = pvr[a];
      const f32x4 q0 = *(const f32x4*)&rowp[a][8 * tx];
      const f32x4 q1 = *(const f32x4*)&rowp[a][8 * tx + 4];
      Rv[0] += pa * q0[0]; Rv[1] += pa * q0[1]; Rv[2] += pa * q0[2]; Rv[3] += pa * q0[3];
      Rv[4] += pa * q1[0]; Rv[5] += pa * q1[1]; Rv[6] += pa * q1[2]; Rv[7] += pa * q1[3];
    }
    if (own_pc) {
#pragma unroll
      for (int jj = 0; jj < 8; ++jj) Rv[jj] = pinv16[ty][8 * (tx & 1) + jj];
    }
    {
      float4 w0 = make_float4(Rv[0], Rv[1], Rv[2], Rv[3]);
      float4 w1 = make_float4(Rv[4], Rv[5], Rv[6], Rv[7]);
      *(float4*)&rext[ty][8 * tx] = w0;
      *(float4*)&rext[ty][8 * tx + 4] = w1;
    }
    __syncthreads();
    if (own_pc) {
#pragma unroll
      for (int ii = 0; ii < 8; ++ii)
#pragma unroll
        for (int jj = 0; jj < 8; ++jj) r[ii][jj] = 0.0f;
    }
#pragma unroll
    for (int a0 = 0; a0 < 16; a0 += 4) {
      float ca[8][4];
#pragma unroll
      for (int ii = 0; ii < 8; ++ii)
        *(float4*)&ca[ii][0] = *(const float4*)&colp[ty + 16 * ii][a0];
#pragma unroll
      for (int ac = 0; ac < 4; ++ac) {
        const f32x4 ra0 = *(const f32x4*)&rext[a0 + ac][8 * tx];
        const f32x4 ra1 = *(const f32x4*)&rext[a0 + ac][8 * tx + 4];
#pragma unroll
        for (int ii = 0; ii < 8; ++ii) {
          const float cv = ca[ii][ac];
          r[ii][0] -= cv * ra0[0]; r[ii][1] -= cv * ra0[1];
          r[ii][2] -= cv * ra0[2]; r[ii][3] -= cv * ra0[3];
          r[ii][4] -= cv * ra1[0]; r[ii][5] -= cv * ra1[1];
          r[ii][6] -= cv * ra1[2]; r[ii][7] -= cv * ra1[3];
        }
      }
    }
#pragma unroll
    for (int ii = 0; ii < 8; ++ii) {
      if (ii == g) {
        const f32x4 ra0 = *(const f32x4*)&rext[ty][8 * tx];
        const f32x4 ra1 = *(const f32x4*)&rext[ty][8 * tx + 4];
        r[ii][0] = ra0[0]; r[ii][1] = ra0[1]; r[ii][2] = ra0[2]; r[ii][3] = ra0[3];
        r[ii][4] = ra1[0]; r[ii][5] = ra1[1]; r[ii][6] = ra1[2]; r[ii][7] = ra1[3];
      }
    }
    __syncthreads();
  }
  // emit Dinv -> Dn (f32), DAn (A-pack direct), DBn (B-pack via Bsh)
  float* dstD = Dn + (size_t)b * NBLK * NBLK;
  __bf16* dA = DAn + (size_t)b * TILEPK;
  __bf16* dB = DBn + (size_t)b * TILEPK;
#pragma unroll
  for (int ii = 0; ii < 8; ++ii) {
    *(float4*)(dstD + (size_t)(ty + 16 * ii) * NBLK + 8 * tx) = *(const float4*)&r[ii][0];
    *(float4*)(dstD + (size_t)(ty + 16 * ii) * NBLK + 8 * tx + 4) = *(const float4*)&r[ii][4];
    bf16x8 hv, lv;
#pragma unroll
    for (int jj = 0; jj < 8; ++jj) {
      const float xv = r[ii][jj];
      const __bf16 h = (__bf16)xv;
      hv[jj] = h;
      lv[jj] = (__bf16)(xv - (float)h);
    }
    const int fiA = ((ii * 4 + (tx & 3)) * 16 + ty) * 8;
    *(bf16x8*)&dA[(size_t)(tx >> 2) * 8192 + fiA] = hv;
    *(bf16x8*)&dA[(size_t)(tx >> 2) * 8192 + 4096 + fiA] = lv;
    *(bf16x8*)&Bsh[ty + 16 * ii][8 * tx] = hv;
  }
  __syncthreads();
#pragma unroll
  for (int g8 = 0; g8 < 8; ++g8) {
    const int gid = g8 * 256 + t;
    const int n15 = gid & 15, q = (gid >> 4) & 3, Ct = (gid >> 6) & 7, ks = gid >> 9;
    const int n = Ct * 16 + n15, k0 = ks * 32 + q * 8;
    bf16x8 v;
#pragma unroll
    for (int j = 0; j < 8; ++j) v[j] = Bsh[k0 + j][n];
    *(bf16x8*)&dB[(size_t)ks * 4096 + (size_t)gid * 8] = v;
  }
  __syncthreads();
#pragma unroll
  for (int ii = 0; ii < 8; ++ii) {
    bf16x8 lv;
#pragma unroll
    for (int jj = 0; jj < 8; ++jj) {
      const float xv = r[ii][jj];
      const __bf16 h = (__bf16)xv;
      lv[jj] = (__bf16)(xv - (float)h);
    }
    *(bf16x8*)&Bsh[ty + 16 * ii][8 * tx] = lv;
  }
  __syncthreads();
#pragma unroll
  for (int g8 = 0; g8 < 8; ++g8) {
    const int gid = g8 * 256 + t;
    const int n15 = gid & 15, q = (gid >> 4) & 3, Ct = (gid >> 6) & 7, ks = gid >> 9;
    const int n = Ct * 16 + n15, k0 = ks * 32 + q * 8;
    bf16x8 v;
#pragma unroll
    for (int j = 0; j < 8; ++j) v[j] = Bsh[k0 + j][n];
    *(bf16x8*)&dB[(size_t)ks * 4096 + (size_t)gid * 8 + 4096] = v;
  }
}

// ---------- final trailing update (kb=7): it != 7, all jt ----------
__global__ void __launch_bounds__(256) kupdate(float* __restrict__ M,
                                               const __bf16* __restrict__ Tpk,
                                               const __bf16* __restrict__ Rpk,
                                               const __bf16* __restrict__ DB, int kb) {
  const int jt = blockIdx.x;
  int it = blockIdx.y; it = (it >= kb) ? it + 1 : it;
  const int b = blockIdx.z;
  float* Ctile = M + ((size_t)b * NPAD + it * NBLK) * NPAD + jt * NBLK;
  const __bf16* pA = Tpk + ((size_t)b * NSTEP + it) * TILEPK;
  if (jt == kb) {
    gemm_pp(pA, DB + (size_t)b * TILEPK, Ctile, NPAD, -1.0f, 0.0f);
  } else {
    gemm_pp(pA, Rpk + ((size_t)b * NSTEP + jt) * TILEPK, Ctile, NPAD, -1.0f, 1.0f);
  }
}

// ---------- K4: epilogue ----------
__global__ void __launch_bounds__(256) kfinal(const float* __restrict__ sc,
                                              const float* __restrict__ Minv,
                                              float* __restrict__ out,
                                              const unsigned long long* __restrict__ mk) {
  __shared__ float Ls[64][65];
  __shared__ float Ds[64];
  const int qt = blockIdx.x, pt = blockIdx.y, b = blockIdx.z;
  const int t = threadIdx.x;
  const unsigned long long key = *mk;
  const float m = dec_key((unsigned int)(key >> 32));
  const unsigned int amax = (unsigned int)key;
  const float* Mb = Minv + (size_t)b * NPAD * NPAD;
  const int q0 = qt * 64, p0 = pt * 64;
  {
    const int pp = t & 63, qq0 = t >> 6;
#pragma unroll
    for (int rp = 0; rp < 16; ++rp) {
      const int qq = qq0 + 4 * rp;
      int rrow = q0 + qq - 1; if (rrow < 0) rrow = 0;
      int ccol = p0 + pp - 1; if (ccol < 0) ccol = 0;
      Ls[qq][pp] = Mb[(size_t)rrow * NPAD + ccol];
    }
    if (t < 64) {
      int cc = p0 + t - 1; if (cc < 0) cc = 0;
      Ds[t] = Mb[(size_t)cc * NPAD + cc];
    }
  }
  __syncthreads();
  const int qq = t & 63, pp0 = t >> 6;
#pragma unroll
  for (int rp = 0; rp < 16; ++rp) {
    const int pp = pp0 + 4 * rp;
    const int p = p0 + pp, q = q0 + qq;
    const size_t off = ((size_t)b * SS + p) * SS + q;
    float val = 0.f;
    if (p >= 1) {
      const float a = expf(sc[off] - m);
      const float g = Ds[pp] - ((q >= 1) ? Ls[qq][pp] : 0.f);
      val = a * g;
    }
    if ((unsigned int)off == amax) val += 16.0f;
    out[off] = val;
  }
}

extern "C" void kernel_launch(void* const* d_in, const int* in_sizes, int n_in,
                              void* d_out, int out_size, void* d_ws, size_t ws_size,
                              hipStream_t stream) {
  const float* sc = (const float*)d_in[0];
  float* out = (float*)d_out;
  char* ws = (char*)d_ws;
  unsigned long long* mk = (unsigned long long*)ws;
  float* M = (float*)(ws + 256);                            // 64 MB
  float* D0 = M + (size_t)BB * NPAD * NPAD;                 // 1 MB
  float* D1 = D0 + (size_t)BB * NBLK * NBLK;                // 1 MB
  __bf16* Tpk0 = (__bf16*)(D1 + (size_t)BB * NBLK * NBLK);  // 8 MB
  __bf16* Tpk1 = Tpk0 + (size_t)BB * NSTEP * TILEPK;        // 8 MB
  __bf16* Rpk = Tpk1 + (size_t)BB * NSTEP * TILEPK;         // 8 MB
  __bf16* DA0 = Rpk + (size_t)BB * NSTEP * TILEPK;          // 1 MB
  __bf16* DA1 = DA0 + (size_t)BB * TILEPK;                  // 1 MB
  __bf16* DB0 = DA1 + (size_t)BB * TILEPK;                  // 1 MB
  __bf16* DB1 = DB0 + (size_t)BB * TILEPK;                  // 1 MB

  hipLaunchKernelGGL(kinit, dim3(1), dim3(64), 0, stream, mk);
  hipLaunchKernelGGL(kmax, dim3(1024), dim3(256), 0, stream, sc, mk);
  hipLaunchKernelGGL(kbuild, dim3(NPAD, BB), dim3(256), 0, stream, sc, M, mk);
  hipLaunchKernelGGL(kcopydiag, dim3(NSTEP * BB + BB), dim3(256), 0, stream,
                     M, Tpk0, D0, DA0, DB0, 0);
  for (int kb = 0; kb < 7; ++kb) {
    const int par = kb & 1;
    float* Dc = par ? D1 : D0;
    __bf16* DAc = par ? DA1 : DA0;
    __bf16* DBc = par ? DB1 : DB0;
    __bf16* Tc = par ? Tpk1 : Tpk0;
    __bf16* Tn = par ? Tpk0 : Tpk1;
    float* Dn = par ? D0 : D1;
    __bf16* DAn = par ? DA0 : DA1;
    __bf16* DBn = par ? DB0 : DB1;
    hipLaunchKernelGGL(kscale, dim3(NSTEP, BB), dim3(256), 0, stream, M, Dc, DAc, Rpk, kb);
    hipLaunchKernelGGL(kfused, dim3(16 + 128 + 784), dim3(256), 0, stream,
                       M, Tc, Tn, Rpk, DBc, Dn, DAn, DBn, kb);
  }
  hipLaunchKernelGGL(kscale, dim3(NSTEP, BB), dim3(256), 0, stream, M, D1, DA1, Rpk, 7);
  hipLaunchKernelGGL(kupdate, dim3(NSTEP, NSTEP - 1, BB), dim3(256), 0, stream,
                     M, Tpk1, Rpk, DB1, 7);
  hipLaunchKernelGGL(kfinal, dim3(16, 16, BB), dim3(256), 0, stream, sc, M, out, mk);
}

// Round 6
// 768.511 us; speedup vs baseline: 1.6310x; 1.6310x over previous
//
#include <hip/hip_runtime.h>

#define BB 16
#define SS 1024
#define NPAD 1024      // padded matrix dim: real 1023 + identity pad row/col
#define NBLK 128
#define NSTEP 8        // NPAD / NBLK
#define TILEPK 32768   // packed bf16 tile: 4 ksteps x (4096 hi + 4096 lo)

typedef __attribute__((ext_vector_type(8))) __bf16 bf16x8;
typedef __attribute__((ext_vector_type(4))) float f32x4;

// ---------- helpers ----------
__device__ __forceinline__ unsigned int enc_f32(float f) {
  unsigned int u = __float_as_uint(f);
  return (u & 0x80000000u) ? ~u : (u | 0x80000000u);
}
__device__ __forceinline__ float dec_key(unsigned int k) {
  unsigned int u = (k & 0x80000000u) ? (k & 0x7fffffffu) : ~k;
  return __uint_as_float(u);
}
// async global->LDS, 16B per lane; LDS dest = wave-uniform base + lane*16
__device__ __forceinline__ void gload16(const __bf16* g, __bf16* l) {
  __builtin_amdgcn_global_load_lds(
      (const __attribute__((address_space(1))) void*)g,
      (__attribute__((address_space(3))) void*)l, 16, 0, 0);
}

// ---------- K0: init max key ----------
__global__ void __launch_bounds__(64) kinit(unsigned long long* mk) { *mk = 0ull; }

// ---------- K1: global max + argmax of scores ----------
__global__ void __launch_bounds__(256) kmax(const float* __restrict__ sc,
                                            unsigned long long* __restrict__ mk) {
  __shared__ unsigned long long red[256];
  const long long n = (long long)BB * SS * SS;
  unsigned long long best = 0ull;
  for (long long i = (long long)blockIdx.x * 256 + threadIdx.x; i < n;
       i += (long long)gridDim.x * 256) {
    unsigned long long k = ((unsigned long long)enc_f32(sc[i]) << 32) | (unsigned int)i;
    if (k > best) best = k;
  }
  red[threadIdx.x] = best;
  __syncthreads();
  for (int s = 128; s > 0; s >>= 1) {
    if ((int)threadIdx.x < s) {
      unsigned long long o = red[threadIdx.x + s];
      if (o > red[threadIdx.x]) red[threadIdx.x] = o;
    }
    __syncthreads();
  }
  if (threadIdx.x == 0) atomicMax(mk, red[0]);
}

// ---------- K2: build padded Laplacian minor M ----------
__global__ void __launch_bounds__(256) kbuild(const float* __restrict__ sc,
                                              float* __restrict__ M,
                                              const unsigned long long* __restrict__ mk) {
  __shared__ float red[256];
  const int r = blockIdx.x;
  const int b = blockIdx.y;
  const int t = threadIdx.x;
  float* Mrow = M + ((size_t)b * NPAD + r) * NPAD;
  if (r == NPAD - 1) {
    for (int c = t; c < NPAD; c += 256) Mrow[c] = (c == NPAD - 1) ? 1.0f : 0.0f;
    return;
  }
  const float m = dec_key((unsigned int)(*mk >> 32));
  const int i = r + 1;
  const float* srow = sc + ((size_t)b * SS + i) * SS;
  float part = 0.f;
  for (int j = t; j < SS; j += 256) part += expf(srow[j] - m);
  red[t] = part;
  __syncthreads();
  for (int s = 128; s > 0; s >>= 1) {
    if (t < s) red[t] += red[t + s];
    __syncthreads();
  }
  const float rs = red[0];
  for (int c = t; c < NPAD; c += 256) {
    float v;
    if (c == NPAD - 1) v = 0.0f;
    else {
      v = -expf(srow[c + 1] - m);
      if (c == r) v += rs;
    }
    Mrow[c] = v;
  }
}

// ---------- prologue K3a+K3b (kb=0 only): pack column 0 + GJ(0) ----------
__global__ void __launch_bounds__(256) kcopydiag(const float* __restrict__ M,
                                                 __bf16* __restrict__ Tpk,
                                                 float* __restrict__ D,
                                                 __bf16* __restrict__ DA,
                                                 __bf16* __restrict__ DB, int kb) {
  const int x = blockIdx.x;
  const int t = threadIdx.x;
  if (x < NSTEP * BB) {
    const int rt = x >> 4, b = x & 15;
    const float* src = M + ((size_t)b * NPAD + rt * NBLK) * NPAD + kb * NBLK;
    __bf16* dst = Tpk + ((size_t)b * NSTEP + rt) * TILEPK;
#pragma unroll
    for (int itr = 0; itr < 8; ++itr) {
      const int gid = itr * 256 + t;
      const int m15 = gid & 15, q = (gid >> 4) & 3, R = (gid >> 6) & 7, ks = gid >> 9;
      const float* sp = src + (size_t)(R * 16 + m15) * NPAD + ks * 32 + q * 8;
      float f[8];
      *(float4*)(f + 0) = *(const float4*)(sp);
      *(float4*)(f + 4) = *(const float4*)(sp + 4);
      bf16x8 hv, lv;
#pragma unroll
      for (int j = 0; j < 8; ++j) {
        const float xv = f[j];
        const __bf16 h = (__bf16)xv;
        hv[j] = h;
        lv[j] = (__bf16)(xv - (float)h);
      }
      const int fi = ((R * 4 + q) * 16 + m15) * 8;
      *(bf16x8*)&dst[(size_t)ks * 8192 + fi] = hv;
      *(bf16x8*)&dst[(size_t)ks * 8192 + 4096 + fi] = lv;
    }
    return;
  }
  __shared__ float ds16[16][16];
  __shared__ float pinv16[16][18];
  __shared__ float rowp[16][128];
  __shared__ float rext[16][128];
  __shared__ float colp[128][20];
  __shared__ __bf16 Bsh[128][130];
  const int b = x - NSTEP * BB;
  const int tx = t & 15, ty = t >> 4;
  const int l = t & 63;
  const int lrow = l & 15, lcg = l >> 4;
  const float* src = M + ((size_t)b * NPAD + kb * NBLK) * NPAD + kb * NBLK;
  float r[8][8];
#pragma unroll
  for (int ii = 0; ii < 8; ++ii) {
    const float* sp = src + (size_t)(ty + 16 * ii) * NPAD + 8 * tx;
    *(float4*)&r[ii][0] = *(const float4*)(sp);
    *(float4*)&r[ii][4] = *(const float4*)(sp + 4);
  }

  for (int g = 0; g < 8; ++g) {
    const bool own_pc = ((tx >> 1) == g);
#pragma unroll
    for (int ii = 0; ii < 8; ++ii) {
      if (ii == g) {
        *(float4*)&rowp[ty][8 * tx] = *(const float4*)&r[ii][0];
        *(float4*)&rowp[ty][8 * tx + 4] = *(const float4*)&r[ii][4];
        if (own_pc) {
          *(float4*)&ds16[ty][8 * (tx & 1)] = *(const float4*)&r[ii][0];
          *(float4*)&ds16[ty][8 * (tx & 1) + 4] = *(const float4*)&r[ii][4];
        }
      }
      if (own_pc) {
        *(float4*)&colp[ty + 16 * ii][8 * (tx & 1)] = *(const float4*)&r[ii][0];
        *(float4*)&colp[ty + 16 * ii][8 * (tx & 1) + 4] = *(const float4*)&r[ii][4];
      }
    }
    __syncthreads();
    float dd[4];
    {
      const f32x4 dv = *(const f32x4*)&ds16[lrow][4 * lcg];
      dd[0] = dv[0]; dd[1] = dv[1]; dd[2] = dv[2]; dd[3] = dv[3];
    }
#pragma unroll
    for (int k = 0; k < 16; ++k) {
      const int pcg = k >> 2, pr = k & 3;
      const float pv = __shfl(dd[pr], k + 16 * pcg);
      const float pinv = __builtin_amdgcn_rcpf(pv);
      const float ck = __shfl(dd[pr], lrow + 16 * pcg);
      float rk[4];
#pragma unroll
      for (int c = 0; c < 4; ++c) rk[c] = __shfl(dd[c], k + 16 * lcg);
      const bool isp = (lrow == k);
      const float cp = ck * pinv;
#pragma unroll
      for (int c = 0; c < 4; ++c) {
        const bool zc = (lcg == pcg) && (c == pr);
        const float upd = (zc ? 0.0f : dd[c]) - cp * (zc ? 1.0f : rk[c]);
        const float prw = zc ? pinv : dd[c] * pinv;
        dd[c] = isp ? prw : upd;
      }
    }
#pragma unroll
    for (int c = 0; c < 4; ++c) pinv16[lrow][4 * lcg + c] = dd[c];
    __syncthreads();
    float pvr[16];
#pragma unroll
    for (int a = 0; a < 16; ++a) pvr[a] = pinv16[ty][a];
    float Rv[8];
#pragma unroll
    for (int jj = 0; jj < 8; ++jj) Rv[jj] = 0.0f;
#pragma unroll
    for (int a = 0; a < 16; ++a) {
      const float pa = pvr[a];
      const f32x4 q0 = *(const f32x4*)&rowp[a][8 * tx];
      const f32x4 q1 = *(const f32x4*)&rowp[a][8 * tx + 4];
      Rv[0] += pa * q0[0]; Rv[1] += pa * q0[1]; Rv[2] += pa * q0[2]; Rv[3] += pa * q0[3];
      Rv[4] += pa * q1[0]; Rv[5] += pa * q1[1]; Rv[6] += pa * q1[2]; Rv[7] += pa * q1[3];
    }
    if (own_pc) {
#pragma unroll
      for (int jj = 0; jj < 8; ++jj) Rv[jj] = pinv16[ty][8 * (tx & 1) + jj];
    }
    {
      float4 w0 = make_float4(Rv[0], Rv[1], Rv[2], Rv[3]);
      float4 w1 = make_float4(Rv[4], Rv[5], Rv[6], Rv[7]);
      *(float4*)&rext[ty][8 * tx] = w0;
      *(float4*)&rext[ty][8 * tx + 4] = w1;
    }
    __syncthreads();
    if (own_pc) {
#pragma unroll
      for (int ii = 0; ii < 8; ++ii)
#pragma unroll
        for (int jj = 0; jj < 8; ++jj) r[ii][jj] = 0.0f;
    }
#pragma unroll
    for (int a0 = 0; a0 < 16; a0 += 4) {
      float ca[8][4];
#pragma unroll
      for (int ii = 0; ii < 8; ++ii)
        *(float4*)&ca[ii][0] = *(const float4*)&colp[ty + 16 * ii][a0];
#pragma unroll
      for (int ac = 0; ac < 4; ++ac) {
        const f32x4 ra0 = *(const f32x4*)&rext[a0 + ac][8 * tx];
        const f32x4 ra1 = *(const f32x4*)&rext[a0 + ac][8 * tx + 4];
#pragma unroll
        for (int ii = 0; ii < 8; ++ii) {
          const float cv = ca[ii][ac];
          r[ii][0] -= cv * ra0[0]; r[ii][1] -= cv * ra0[1];
          r[ii][2] -= cv * ra0[2]; r[ii][3] -= cv * ra0[3];
          r[ii][4] -= cv * ra1[0]; r[ii][5] -= cv * ra1[1];
          r[ii][6] -= cv * ra1[2]; r[ii][7] -= cv * ra1[3];
        }
      }
    }
#pragma unroll
    for (int ii = 0; ii < 8; ++ii) {
      if (ii == g) {
        const f32x4 ra0 = *(const f32x4*)&rext[ty][8 * tx];
        const f32x4 ra1 = *(const f32x4*)&rext[ty][8 * tx + 4];
        r[ii][0] = ra0[0]; r[ii][1] = ra0[1]; r[ii][2] = ra0[2]; r[ii][3] = ra0[3];
        r[ii][4] = ra1[0]; r[ii][5] = ra1[1]; r[ii][6] = ra1[2]; r[ii][7] = ra1[3];
      }
    }
    __syncthreads();
  }
  float* dst = D + (size_t)b * NBLK * NBLK;
  __bf16* dA = DA + (size_t)b * TILEPK;
  __bf16* dB = DB + (size_t)b * TILEPK;
#pragma unroll
  for (int ii = 0; ii < 8; ++ii) {
    *(float4*)(dst + (size_t)(ty + 16 * ii) * NBLK + 8 * tx) = *(const float4*)&r[ii][0];
    *(float4*)(dst + (size_t)(ty + 16 * ii) * NBLK + 8 * tx + 4) = *(const float4*)&r[ii][4];
    bf16x8 hv;
#pragma unroll
    for (int jj = 0; jj < 8; ++jj) {
      const float xv = r[ii][jj];
      const __bf16 h = (__bf16)xv;
      hv[jj] = h;
    }
    const int fiA = ((ii * 4 + (tx & 3)) * 16 + ty) * 8;
    bf16x8 lv;
#pragma unroll
    for (int jj = 0; jj < 8; ++jj) lv[jj] = (__bf16)(r[ii][jj] - (float)hv[jj]);
    *(bf16x8*)&dA[(size_t)(tx >> 2) * 8192 + fiA] = hv;
    *(bf16x8*)&dA[(size_t)(tx >> 2) * 8192 + 4096 + fiA] = lv;
    *(bf16x8*)&Bsh[ty + 16 * ii][8 * tx] = hv;
  }
  __syncthreads();
#pragma unroll
  for (int g8 = 0; g8 < 8; ++g8) {
    const int gid = g8 * 256 + t;
    const int n15 = gid & 15, q = (gid >> 4) & 3, Ct = (gid >> 6) & 7, ks = gid >> 9;
    const int n = Ct * 16 + n15, k0 = ks * 32 + q * 8;
    bf16x8 v;
#pragma unroll
    for (int j = 0; j < 8; ++j) v[j] = Bsh[k0 + j][n];
    *(bf16x8*)&dB[(size_t)ks * 4096 + (size_t)gid * 8] = v;
  }
  __syncthreads();
#pragma unroll
  for (int ii = 0; ii < 8; ++ii) {
    bf16x8 lv;
#pragma unroll
    for (int jj = 0; jj < 8; ++jj) {
      const float xv = r[ii][jj];
      const __bf16 h = (__bf16)xv;
      lv[jj] = (__bf16)(xv - (float)h);
    }
    *(bf16x8*)&Bsh[ty + 16 * ii][8 * tx] = lv;
  }
  __syncthreads();
#pragma unroll
  for (int g8 = 0; g8 < 8; ++g8) {
    const int gid = g8 * 256 + t;
    const int n15 = gid & 15, q = (gid >> 4) & 3, Ct = (gid >> 6) & 7, ks = gid >> 9;
    const int n = Ct * 16 + n15, k0 = ks * 32 + q * 8;
    bf16x8 v;
#pragma unroll
    for (int j = 0; j < 8; ++j) v[j] = Bsh[k0 + j][n];
    *(bf16x8*)&dB[(size_t)ks * 4096 + (size_t)gid * 8 + 4096] = v;
  }
}

// ---------- packed-input MFMA accumulate into caller acc (smem-carved staging) ----------
__device__ __forceinline__ void gemm_acc(const __bf16* __restrict__ pA,
                                         const __bf16* __restrict__ pB,
                                         char* smem, f32x4 acc[4][4]) {
  const int t = threadIdx.x;
  const int l = t & 63, w = t >> 6;
  const int rbase = (w & 1) * 4, cbase = (w >> 1) * 4;
  __bf16* sAb[2] = {(__bf16*)smem, (__bf16*)(smem + 16384)};
  __bf16* sBb[2] = {(__bf16*)(smem + 32768), (__bf16*)(smem + 49152)};
  {
    const __bf16* gA = pA + (size_t)w * 2048 + l * 8;
    const __bf16* gB = pB + (size_t)w * 2048 + l * 8;
#pragma unroll
    for (int i = 0; i < 4; ++i) {
      gload16(gA + i * 512, sAb[0] + w * 2048 + i * 512);
      gload16(gB + i * 512, sBb[0] + w * 2048 + i * 512);
    }
  }
  __syncthreads();
#pragma unroll
  for (int ks = 0; ks < 4; ++ks) {
    const int buf = ks & 1;
    if (ks < 3) {
      const __bf16* gA = pA + (size_t)(ks + 1) * 8192 + w * 2048 + l * 8;
      const __bf16* gB = pB + (size_t)(ks + 1) * 8192 + w * 2048 + l * 8;
#pragma unroll
      for (int i = 0; i < 4; ++i) {
        gload16(gA + i * 512, sAb[buf ^ 1] + w * 2048 + i * 512);
        gload16(gB + i * 512, sBb[buf ^ 1] + w * 2048 + i * 512);
      }
    }
    bf16x8 a_h[4], a_l[4];
#pragma unroll
    for (int rt = 0; rt < 4; ++rt) {
      a_h[rt] = *(const bf16x8*)&sAb[buf][(size_t)((rbase + rt) * 64 + l) * 8];
      a_l[rt] = *(const bf16x8*)&sAb[buf][4096 + (size_t)((rbase + rt) * 64 + l) * 8];
    }
#pragma unroll
    for (int ct = 0; ct < 4; ++ct) {
      bf16x8 b_h = *(const bf16x8*)&sBb[buf][(size_t)((cbase + ct) * 64 + l) * 8];
      bf16x8 b_l = *(const bf16x8*)&sBb[buf][4096 + (size_t)((cbase + ct) * 64 + l) * 8];
#pragma unroll
      for (int rt = 0; rt < 4; ++rt) {
        acc[rt][ct] = __builtin_amdgcn_mfma_f32_16x16x32_bf16(a_h[rt], b_h, acc[rt][ct], 0, 0, 0);
        acc[rt][ct] = __builtin_amdgcn_mfma_f32_16x16x32_bf16(a_h[rt], b_l, acc[rt][ct], 0, 0, 0);
        acc[rt][ct] = __builtin_amdgcn_mfma_f32_16x16x32_bf16(a_l[rt], b_h, acc[rt][ct], 0, 0, 0);
      }
    }
    if (ks < 3) __syncthreads();
  }
}

// ---------- standalone packed GEMM (final kupdate): C = beta*C + alpha*A*B ----------
__device__ __forceinline__ void gemm_pp(const __bf16* __restrict__ pA,
                                        const __bf16* __restrict__ pB,
                                        float* __restrict__ C, int ldc,
                                        float alpha, float beta) {
  __shared__ __align__(16) char smem_pp[65536];
  const int t = threadIdx.x;
  const int l = t & 63, w = t >> 6;
  f32x4 acc[4][4];
#pragma unroll
  for (int i = 0; i < 4; i++)
#pragma unroll
    for (int j = 0; j < 4; j++) acc[i][j] = (f32x4){0.f, 0.f, 0.f, 0.f};
  gemm_acc(pA, pB, smem_pp, acc);
  const int row0 = (w & 1) * 64 + ((l >> 4) << 2);
  const int col0 = (w >> 1) * 64 + (l & 15);
  if (beta == 0.0f) {
#pragma unroll
    for (int rt = 0; rt < 4; ++rt)
#pragma unroll
      for (int ct = 0; ct < 4; ++ct)
#pragma unroll
        for (int r = 0; r < 4; ++r)
          C[(size_t)(row0 + rt * 16 + r) * ldc + col0 + ct * 16] = alpha * acc[rt][ct][r];
  } else {
#pragma unroll
    for (int rt = 0; rt < 4; ++rt)
#pragma unroll
      for (int ct = 0; ct < 4; ++ct)
#pragma unroll
        for (int r = 0; r < 4; ++r) {
          float* cp = C + (size_t)(row0 + rt * 16 + r) * ldc + col0 + ct * 16;
          *cp = beta * (*cp) + alpha * acc[rt][ct][r];
        }
  }
}

// ---------- K3c: pivot block-row scale: B' = Dinv * B ----------
__global__ void __launch_bounds__(256) kscale(float* __restrict__ M,
                                              const float* __restrict__ D,
                                              const __bf16* __restrict__ DA,
                                              __bf16* __restrict__ Rpk, int kb) {
  const int jt = blockIdx.x, b = blockIdx.y;
  float* Mb = M + (size_t)b * NPAD * NPAD;
  const int t = threadIdx.x;
  if (jt == kb) {
    const float* Dinv = D + (size_t)b * NBLK * NBLK;
    const int c = (t & 31) * 4, r0 = t >> 5;
    float* dst = Mb + (size_t)(kb * NBLK) * NPAD + kb * NBLK;
    for (int r = r0; r < NBLK; r += 8)
      *(float4*)(dst + (size_t)r * NPAD + c) = *(const float4*)(Dinv + r * NBLK + c);
    return;
  }
  __shared__ __bf16 sA[8192];
  __shared__ __bf16 Bh[4096], Bl[4096];
  __shared__ __bf16 Bsh[128][130];
  const int l = t & 63, w = t >> 6;
  const int ic = t & 127, kh = t >> 7;
  const int rbase = (w & 1) * 4, cbase = (w >> 1) * 4;
  const __bf16* pA = DA + (size_t)b * TILEPK;
  float* Btile = Mb + (size_t)(kb * NBLK) * NPAD + jt * NBLK;

  f32x4 acc[4][4];
#pragma unroll
  for (int i = 0; i < 4; i++)
#pragma unroll
    for (int j = 0; j < 4; j++) acc[i][j] = (f32x4){0.f, 0.f, 0.f, 0.f};

  for (int ks = 0; ks < 4; ++ks) {
    const __bf16* gA = pA + (size_t)ks * 8192 + w * 2048 + l * 8;
#pragma unroll
    for (int i = 0; i < 4; ++i) gload16(gA + i * 512, &sA[w * 2048 + i * 512]);
    {
      const float* bp = Btile + (size_t)(ks * 32 + kh * 16) * NPAD + ic;
      float f[16];
#pragma unroll
      for (int kk = 0; kk < 16; ++kk) f[kk] = bp[(size_t)kk * NPAD];
      const int base = ((ic >> 4) * 4 + kh * 2) * 16 + (ic & 15);
#pragma unroll
      for (int g = 0; g < 2; ++g) {
        bf16x8 hv, lv;
#pragma unroll
        for (int j = 0; j < 8; ++j) {
          const float xv = f[g * 8 + j];
          const __bf16 h = (__bf16)xv;
          hv[j] = h;
          lv[j] = (__bf16)(xv - (float)h);
        }
        *(bf16x8*)&Bh[(size_t)(base + g * 16) * 8] = hv;
        *(bf16x8*)&Bl[(size_t)(base + g * 16) * 8] = lv;
      }
    }
    __syncthreads();
    bf16x8 a_h[4], a_l[4];
#pragma unroll
    for (int rt = 0; rt < 4; ++rt) {
      a_h[rt] = *(const bf16x8*)&sA[(size_t)((rbase + rt) * 64 + l) * 8];
      a_l[rt] = *(const bf16x8*)&sA[4096 + (size_t)((rbase + rt) * 64 + l) * 8];
    }
#pragma unroll
    for (int ct = 0; ct < 4; ++ct) {
      bf16x8 b_h = *(const bf16x8*)&Bh[(size_t)((cbase + ct) * 64 + l) * 8];
      bf16x8 b_l = *(const bf16x8*)&Bl[(size_t)((cbase + ct) * 64 + l) * 8];
#pragma unroll
      for (int rt = 0; rt < 4; ++rt) {
        acc[rt][ct] = __builtin_amdgcn_mfma_f32_16x16x32_bf16(a_h[rt], b_h, acc[rt][ct], 0, 0, 0);
        acc[rt][ct] = __builtin_amdgcn_mfma_f32_16x16x32_bf16(a_h[rt], b_l, acc[rt][ct], 0, 0, 0);
        acc[rt][ct] = __builtin_amdgcn_mfma_f32_16x16x32_bf16(a_l[rt], b_h, acc[rt][ct], 0, 0, 0);
      }
    }
    __syncthreads();
  }
  __bf16* Rt = Rpk + ((size_t)b * NSTEP + jt) * TILEPK;
  const int row0 = (w & 1) * 64 + ((l >> 4) << 2);
  const int col0 = (w >> 1) * 64 + (l & 15);
#pragma unroll
  for (int rt = 0; rt < 4; ++rt)
#pragma unroll
    for (int ct = 0; ct < 4; ++ct)
#pragma unroll
      for (int rr = 0; rr < 4; ++rr) {
        const float v = acc[rt][ct][rr];
        const int row = row0 + rt * 16 + rr;
        const int col = col0 + ct * 16;
        Btile[(size_t)row * NPAD + col] = v;
        Bsh[row][col] = (__bf16)v;
      }
  __syncthreads();
#pragma unroll
  for (int g8 = 0; g8 < 8; ++g8) {
    const int gid = g8 * 256 + t;
    const int n15 = gid & 15, q = (gid >> 4) & 3, Ct = (gid >> 6) & 7, ks = gid >> 9;
    const int n = Ct * 16 + n15, k0 = ks * 32 + q * 8;
    bf16x8 v;
#pragma unroll
    for (int j = 0; j < 8; ++j) v[j] = Bsh[k0 + j][n];
    *(bf16x8*)&Rt[(size_t)ks * 4096 + (size_t)gid * 8] = v;
  }
  __syncthreads();
#pragma unroll
  for (int rt = 0; rt < 4; ++rt)
#pragma unroll
    for (int ct = 0; ct < 4; ++ct)
#pragma unroll
      for (int rr = 0; rr < 4; ++rr) {
        const float v = acc[rt][ct][rr];
        const int row = row0 + rt * 16 + rr;
        const int col = col0 + ct * 16;
        const __bf16 h = (__bf16)v;
        Bsh[row][col] = (__bf16)(v - (float)h);
      }
  __syncthreads();
#pragma unroll
  for (int g8 = 0; g8 < 8; ++g8) {
    const int gid = g8 * 256 + t;
    const int n15 = gid & 15, q = (gid >> 4) & 3, Ct = (gid >> 6) & 7, ks = gid >> 9;
    const int n = Ct * 16 + n15, k0 = ks * 32 + q * 8;
    bf16x8 v;
#pragma unroll
    for (int j = 0; j < 8; ++j) v[j] = Bsh[k0 + j][n];
    *(bf16x8*)&Rt[(size_t)ks * 4096 + (size_t)gid * 8 + 4096] = v;
  }
}

// ---------- fused step kernel: x<16 GJ(kb+1, self-update) | 16..144 pack col kb+1 |
//            x>=144 trailing update (it!=kb, jt!=kb+1) ----------
__global__ void __launch_bounds__(256) kfused(
    float* __restrict__ M,
    const __bf16* __restrict__ Tcur, __bf16* __restrict__ Tnxt,
    const __bf16* __restrict__ Rpk, const __bf16* __restrict__ DBc,
    float* __restrict__ Dn, __bf16* __restrict__ DAn, __bf16* __restrict__ DBn,
    int kb) {
  __shared__ __align__(16) char smem[65536];
  const int x = blockIdx.x;
  const int t = threadIdx.x;
  const int l = t & 63, w = t >> 6;
  const int row0 = (w & 1) * 64 + ((l >> 4) << 2);
  const int col0 = (w >> 1) * 64 + (l & 15);
  const int kd = kb + 1;

  if (x >= 144) {
    // ---- trailing update ----
    const int idx = x - 144;
    const int b = idx & 15, rem = idx >> 4;  // 0..48
    const int jt7 = rem % 7, it7 = rem / 7;
    const int jt = jt7 + (jt7 >= kd);
    const int it = it7 + (it7 >= kb);
    f32x4 acc[4][4];
#pragma unroll
    for (int i = 0; i < 4; i++)
#pragma unroll
      for (int j = 0; j < 4; j++) acc[i][j] = (f32x4){0.f, 0.f, 0.f, 0.f};
    const __bf16* pA = Tcur + ((size_t)b * NSTEP + it) * TILEPK;
    const __bf16* pB = (jt == kb) ? (DBc + (size_t)b * TILEPK)
                                  : (Rpk + ((size_t)b * NSTEP + jt) * TILEPK);
    gemm_acc(pA, pB, smem, acc);
    float* C = M + ((size_t)b * NPAD + it * NBLK) * NPAD + jt * NBLK;
    if (jt == kb) {
#pragma unroll
      for (int pt = 0; pt < 4; ++pt)
#pragma unroll
        for (int ct = 0; ct < 4; ++ct)
#pragma unroll
          for (int rr = 0; rr < 4; ++rr)
            C[(size_t)(row0 + pt * 16 + rr) * NPAD + col0 + ct * 16] = -acc[pt][ct][rr];
    } else {
#pragma unroll
      for (int pt = 0; pt < 4; ++pt)
#pragma unroll
        for (int ct = 0; ct < 4; ++ct)
#pragma unroll
          for (int rr = 0; rr < 4; ++rr) {
            float* cp = C + (size_t)(row0 + pt * 16 + rr) * NPAD + col0 + ct * 16;
            *cp = *cp - acc[pt][ct][rr];
          }
    }
    return;
  }

  if (x >= 16) {
    // ---- self-updating pack of column kd into Tnxt (A-layout) ----
    const int p = x - 16;
    const int rt = p >> 4, b = p & 15;
    f32x4 acc[4][4];
#pragma unroll
    for (int i = 0; i < 4; i++)
#pragma unroll
      for (int j = 0; j < 4; j++) acc[i][j] = (f32x4){0.f, 0.f, 0.f, 0.f};
    if (rt != kb) {  // pivot row (rt==kb) gets no update
      gemm_acc(Tcur + ((size_t)b * NSTEP + rt) * TILEPK,
               Rpk + ((size_t)b * NSTEP + kd) * TILEPK, smem, acc);
    }
    __syncthreads();  // staging dead
    // park Csrc - acc in full-smem f32 [128][128] (MFMA mapping, coalesced global read)
    float(*Msh)[128] = (float(*)[128])smem;
    const float* Csrc = M + ((size_t)b * NPAD + rt * NBLK) * NPAD + kd * NBLK;
#pragma unroll
    for (int pt = 0; pt < 4; ++pt)
#pragma unroll
      for (int ct = 0; ct < 4; ++ct)
#pragma unroll
        for (int rr = 0; rr < 4; ++rr)
          Msh[row0 + pt * 16 + rr][col0 + ct * 16] =
              Csrc[(size_t)(row0 + pt * 16 + rr) * NPAD + col0 + ct * 16] - acc[pt][ct][rr];
    __syncthreads();
    // single-pass A-pack emission (hi+lo) from Msh
    __bf16* dst = Tnxt + ((size_t)b * NSTEP + rt) * TILEPK;
#pragma unroll
    for (int g8 = 0; g8 < 8; ++g8) {
      const int gid = g8 * 256 + t;
      const int m15 = gid & 15, q = (gid >> 4) & 3, R = (gid >> 6) & 7, ks = gid >> 9;
      const int m = R * 16 + m15, k0 = ks * 32 + q * 8;
      bf16x8 hv, lv;
#pragma unroll
      for (int j = 0; j < 8; ++j) {
        const float xv = Msh[m][k0 + j];
        const __bf16 h = (__bf16)xv;
        hv[j] = h;
        lv[j] = (__bf16)(xv - (float)h);
      }
      *(bf16x8*)&dst[(size_t)ks * 4096 + (size_t)gid * 8] = hv;
      *(bf16x8*)&dst[(size_t)ks * 4096 + (size_t)gid * 8 + 4096] = lv;
    }
    return;
  }

  // ---- GJ(kd) with self-update: r = Mdiag - Tcur(kd)*Rpk(kd) ----
  const int b = x;
  const int tx = t & 15, ty = t >> 4;
  const int lrow = l & 15, lcg = l >> 4;
  f32x4 acc[4][4];
#pragma unroll
  for (int i = 0; i < 4; i++)
#pragma unroll
    for (int j = 0; j < 4; j++) acc[i][j] = (f32x4){0.f, 0.f, 0.f, 0.f};
  gemm_acc(Tcur + ((size_t)b * NSTEP + kd) * TILEPK,
           Rpk + ((size_t)b * NSTEP + kd) * TILEPK, smem, acc);
  __syncthreads();  // staging dead

  // park acc in full-smem f32 [128][128]; acc dies before r is born (reg pressure)
  {
    float(*Msh)[128] = (float(*)[128])smem;
#pragma unroll
    for (int pt = 0; pt < 4; ++pt)
#pragma unroll
      for (int ct = 0; ct < 4; ++ct)
#pragma unroll
        for (int rr = 0; rr < 4; ++rr)
          Msh[row0 + pt * 16 + rr][col0 + ct * 16] = acc[pt][ct][rr];
  }
  __syncthreads();
  const float* src = M + ((size_t)b * NPAD + kd * NBLK) * NPAD + kd * NBLK;
  float r[8][8];
  {
    float(*Msh)[128] = (float(*)[128])smem;
#pragma unroll
    for (int ii = 0; ii < 8; ++ii) {
      const float* sp = src + (size_t)(ty + 16 * ii) * NPAD + 8 * tx;
      const float4 m0 = *(const float4*)sp;
      const float4 m1 = *(const float4*)(sp + 4);
      const float* mr = &Msh[ty + 16 * ii][8 * tx];
      r[ii][0] = m0.x - mr[0]; r[ii][1] = m0.y - mr[1];
      r[ii][2] = m0.z - mr[2]; r[ii][3] = m0.w - mr[3];
      r[ii][4] = m1.x - mr[4]; r[ii][5] = m1.y - mr[5];
      r[ii][6] = m1.z - mr[6]; r[ii][7] = m1.w - mr[7];
    }
  }
  __syncthreads();  // Msh dead; GJ carving begins

  float(*rowp)[128] = (float(*)[128])(smem);
  float(*rext)[128] = (float(*)[128])(smem + 8192);
  float(*colp)[20] = (float(*)[20])(smem + 16384);
  float(*ds16)[16] = (float(*)[16])(smem + 26624);
  float(*pinv16)[18] = (float(*)[18])(smem + 27648);
  __bf16(*Bsh)[136] = (__bf16(*)[136])(smem + 28800);

  for (int g = 0; g < 8; ++g) {
    const bool own_pc = ((tx >> 1) == g);
#pragma unroll
    for (int ii = 0; ii < 8; ++ii) {
      if (ii == g) {
        *(float4*)&rowp[ty][8 * tx] = *(const float4*)&r[ii][0];
        *(float4*)&rowp[ty][8 * tx + 4] = *(const float4*)&r[ii][4];
        if (own_pc) {
          *(float4*)&ds16[ty][8 * (tx & 1)] = *(const float4*)&r[ii][0];
          *(float4*)&ds16[ty][8 * (tx & 1) + 4] = *(const float4*)&r[ii][4];
        }
      }
      if (own_pc) {
        *(float4*)&colp[ty + 16 * ii][8 * (tx & 1)] = *(const float4*)&r[ii][0];
        *(float4*)&colp[ty + 16 * ii][8 * (tx & 1) + 4] = *(const float4*)&r[ii][4];
      }
    }
    __syncthreads();
    float dd[4];
    {
      const f32x4 dv = *(const f32x4*)&ds16[lrow][4 * lcg];
      dd[0] = dv[0]; dd[1] = dv[1]; dd[2] = dv[2]; dd[3] = dv[3];
    }
#pragma unroll
    for (int k = 0; k < 16; ++k) {
      const int pcg = k >> 2, pr = k & 3;
      const float pv = __shfl(dd[pr], k + 16 * pcg);
      const float pinv = __builtin_amdgcn_rcpf(pv);
      const float ck = __shfl(dd[pr], lrow + 16 * pcg);
      float rk[4];
#pragma unroll
      for (int c = 0; c < 4; ++c) rk[c] = __shfl(dd[c], k + 16 * lcg);
      const bool isp = (lrow == k);
      const float cp = ck * pinv;
#pragma unroll
      for (int c = 0; c < 4; ++c) {
        const bool zc = (lcg == pcg) && (c == pr);
        const float upd = (zc ? 0.0f : dd[c]) - cp * (zc ? 1.0f : rk[c]);
        const float prw = zc ? pinv : dd[c] * pinv;
        dd[c] = isp ? prw : upd;
      }
    }
#pragma unroll
    for (int c = 0; c < 4; ++c) pinv16[lrow][4 * lcg + c] = dd[c];
    __syncthreads();
    float pvr[16];
#pragma unroll
    for (int a = 0; a < 16; ++a) pvr[a] = pinv16[ty][a];
    float Rv[8];
#pragma unroll
    for (int jj = 0; jj < 8; ++jj) Rv[jj] = 0.0f;
#pragma unroll
    for (int a = 0; a < 16; ++a) {
      const float pa = pvr[a];
      const f32x4 q0 = *(const f32x4*)&rowp[a][8 * tx];
      const f32x4 q1 = *(const f32x4*)&rowp[a][8 * tx + 4];
      Rv[0] += pa * q0[0]; Rv[1] += pa * q0[1]; Rv[2] += pa * q0[2]; Rv[3] += pa * q0[3];
      Rv[4] += pa * q1[0]; Rv[5] += pa * q1[1]; Rv[6] += pa * q1[2]; Rv[7] += pa * q1[3];
    }
    if (own_pc) {
#pragma unroll
      for (int jj = 0; jj < 8; ++jj) Rv[jj] = pinv16[ty][8 * (tx & 1) + jj];
    }
    {
      float4 w0 = make_float4(Rv[0], Rv[1], Rv[2], Rv[3]);
      float4 w1 = make_float4(Rv[4], Rv[5], Rv[6], Rv[7]);
      *(float4*)&rext[ty][8 * tx] = w0;
      *(float4*)&rext[ty][8 * tx + 4] = w1;
    }
    __syncthreads();
    if (own_pc) {
#pragma unroll
      for (int ii = 0; ii < 8; ++ii)
#pragma unroll
        for (int jj = 0; jj < 8; ++jj) r[ii][jj] = 0.0f;
    }
#pragma unroll
    for (int a0 = 0; a0 < 16; a0 += 4) {
      float ca[8][4];
#pragma unroll
      for (int ii = 0; ii < 8; ++ii)
        *(float4*)&ca[ii][0] = *(const float4*)&colp[ty + 16 * ii][a0];
#pragma unroll
      for (int ac = 0; ac < 4; ++ac) {
        const f32x4 ra0 = *(const f32x4*)&rext[a0 + ac][8 * tx];
        const f32x4 ra1 = *(const f32x4*)&rext[a0 + ac][8 * tx + 4];
#pragma unroll
        for (int ii = 0; ii < 8; ++ii) {
          const float cv = ca[ii][ac];
          r[ii][0] -= cv * ra0[0]; r[ii][1] -= cv * ra0[1];
          r[ii][2] -= cv * ra0[2]; r[ii][3] -= cv * ra0[3];
          r[ii][4] -= cv * ra1[0]; r[ii][5] -= cv * ra1[1];
          r[ii][6] -= cv * ra1[2]; r[ii][7] -= cv * ra1[3];
        }
      }
    }
#pragma unroll
    for (int ii = 0; ii < 8; ++ii) {
      if (ii == g) {
        const f32x4 ra0 = *(const f32x4*)&rext[ty][8 * tx];
        const f32x4 ra1 = *(const f32x4*)&rext[ty][8 * tx + 4];
        r[ii][0] = ra0[0]; r[ii][1] = ra0[1]; r[ii][2] = ra0[2]; r[ii][3] = ra0[3];
        r[ii][4] = ra1[0]; r[ii][5] = ra1[1]; r[ii][6] = ra1[2]; r[ii][7] = ra1[3];
      }
    }
    __syncthreads();
  }
  // emit Dinv -> Dn (f32), DAn (A-pack direct), DBn (B-pack via Bsh)
  float* dstD = Dn + (size_t)b * NBLK * NBLK;
  __bf16* dA = DAn + (size_t)b * TILEPK;
  __bf16* dB = DBn + (size_t)b * TILEPK;
#pragma unroll
  for (int ii = 0; ii < 8; ++ii) {
    *(float4*)(dstD + (size_t)(ty + 16 * ii) * NBLK + 8 * tx) = *(const float4*)&r[ii][0];
    *(float4*)(dstD + (size_t)(ty + 16 * ii) * NBLK + 8 * tx + 4) = *(const float4*)&r[ii][4];
    bf16x8 hv, lv;
#pragma unroll
    for (int jj = 0; jj < 8; ++jj) {
      const float xv = r[ii][jj];
      const __bf16 h = (__bf16)xv;
      hv[jj] = h;
      lv[jj] = (__bf16)(xv - (float)h);
    }
    const int fiA = ((ii * 4 + (tx & 3)) * 16 + ty) * 8;
    *(bf16x8*)&dA[(size_t)(tx >> 2) * 8192 + fiA] = hv;
    *(bf16x8*)&dA[(size_t)(tx >> 2) * 8192 + 4096 + fiA] = lv;
    *(bf16x8*)&Bsh[ty + 16 * ii][8 * tx] = hv;
  }
  __syncthreads();
#pragma unroll
  for (int g8 = 0; g8 < 8; ++g8) {
    const int gid = g8 * 256 + t;
    const int n15 = gid & 15, q = (gid >> 4) & 3, Ct = (gid >> 6) & 7, ks = gid >> 9;
    const int n = Ct * 16 + n15, k0 = ks * 32 + q * 8;
    bf16x8 v;
#pragma unroll
    for (int j = 0; j < 8; ++j) v[j] = Bsh[k0 + j][n];
    *(bf16x8*)&dB[(size_t)ks * 4096 + (size_t)gid * 8] = v;
  }
  __syncthreads();
#pragma unroll
  for (int ii = 0; ii < 8; ++ii) {
    bf16x8 lv;
#pragma unroll
    for (int jj = 0; jj < 8; ++jj) {
      const float xv = r[ii][jj];
      const __bf16 h = (__bf16)xv;
      lv[jj] = (__bf16)(xv - (float)h);
    }
    *(bf16x8*)&Bsh[ty + 16 * ii][8 * tx] = lv;
  }
  __syncthreads();
#pragma unroll
  for (int g8 = 0; g8 < 8; ++g8) {
    const int gid = g8 * 256 + t;
    const int n15 = gid & 15, q = (gid >> 4) & 3, Ct = (gid >> 6) & 7, ks = gid >> 9;
    const int n = Ct * 16 + n15, k0 = ks * 32 + q * 8;
    bf16x8 v;
#pragma unroll
    for (int j = 0; j < 8; ++j) v[j] = Bsh[k0 + j][n];
    *(bf16x8*)&dB[(size_t)ks * 4096 + (size_t)gid * 8 + 4096] = v;
  }
}

// ---------- final trailing update (kb=7): it != 7, all jt ----------
__global__ void __launch_bounds__(256) kupdate(float* __restrict__ M,
                                               const __bf16* __restrict__ Tpk,
                                               const __bf16* __restrict__ Rpk,
                                               const __bf16* __restrict__ DB, int kb) {
  const int jt = blockIdx.x;
  int it = blockIdx.y; it = (it >= kb) ? it + 1 : it;
  const int b = blockIdx.z;
  float* Ctile = M + ((size_t)b * NPAD + it * NBLK) * NPAD + jt * NBLK;
  const __bf16* pA = Tpk + ((size_t)b * NSTEP + it) * TILEPK;
  if (jt == kb) {
    gemm_pp(pA, DB + (size_t)b * TILEPK, Ctile, NPAD, -1.0f, 0.0f);
  } else {
    gemm_pp(pA, Rpk + ((size_t)b * NSTEP + jt) * TILEPK, Ctile, NPAD, -1.0f, 1.0f);
  }
}

// ---------- K4: epilogue ----------
__global__ void __launch_bounds__(256) kfinal(const float* __restrict__ sc,
                                              const float* __restrict__ Minv,
                                              float* __restrict__ out,
                                              const unsigned long long* __restrict__ mk) {
  __shared__ float Ls[64][65];
  __shared__ float Ds[64];
  const int qt = blockIdx.x, pt = blockIdx.y, b = blockIdx.z;
  const int t = threadIdx.x;
  const unsigned long long key = *mk;
  const float m = dec_key((unsigned int)(key >> 32));
  const unsigned int amax = (unsigned int)key;
  const float* Mb = Minv + (size_t)b * NPAD * NPAD;
  const int q0 = qt * 64, p0 = pt * 64;
  {
    const int pp = t & 63, qq0 = t >> 6;
#pragma unroll
    for (int rp = 0; rp < 16; ++rp) {
      const int qq = qq0 + 4 * rp;
      int rrow = q0 + qq - 1; if (rrow < 0) rrow = 0;
      int ccol = p0 + pp - 1; if (ccol < 0) ccol = 0;
      Ls[qq][pp] = Mb[(size_t)rrow * NPAD + ccol];
    }
    if (t < 64) {
      int cc = p0 + t - 1; if (cc < 0) cc = 0;
      Ds[t] = Mb[(size_t)cc * NPAD + cc];
    }
  }
  __syncthreads();
  const int qq = t & 63, pp0 = t >> 6;
#pragma unroll
  for (int rp = 0; rp < 16; ++rp) {
    const int pp = pp0 + 4 * rp;
    const int p = p0 + pp, q = q0 + qq;
    const size_t off = ((size_t)b * SS + p) * SS + q;
    float val = 0.f;
    if (p >= 1) {
      const float a = expf(sc[off] - m);
      const float g = Ds[pp] - ((q >= 1) ? Ls[qq][pp] : 0.f);
      val = a * g;
    }
    if ((unsigned int)off == amax) val += 16.0f;
    out[off] = val;
  }
}

extern "C" void kernel_launch(void* const* d_in, const int* in_sizes, int n_in,
                              void* d_out, int out_size, void* d_ws, size_t ws_size,
                              hipStream_t stream) {
  const float* sc = (const float*)d_in[0];
  float* out = (float*)d_out;
  char* ws = (char*)d_ws;
  unsigned long long* mk = (unsigned long long*)ws;
  float* M = (float*)(ws + 256);                            // 64 MB
  float* D0 = M + (size_t)BB * NPAD * NPAD;                 // 1 MB
  float* D1 = D0 + (size_t)BB * NBLK * NBLK;                // 1 MB
  __bf16* Tpk0 = (__bf16*)(D1 + (size_t)BB * NBLK * NBLK);  // 8 MB
  __bf16* Tpk1 = Tpk0 + (size_t)BB * NSTEP * TILEPK;        // 8 MB
  __bf16* Rpk = Tpk1 + (size_t)BB * NSTEP * TILEPK;         // 8 MB
  __bf16* DA0 = Rpk + (size_t)BB * NSTEP * TILEPK;          // 1 MB
  __bf16* DA1 = DA0 + (size_t)BB * TILEPK;                  // 1 MB
  __bf16* DB0 = DA1 + (size_t)BB * TILEPK;                  // 1 MB
  __bf16* DB1 = DB0 + (size_t)BB * TILEPK;                  // 1 MB

  hipLaunchKernelGGL(kinit, dim3(1), dim3(64), 0, stream, mk);
  hipLaunchKernelGGL(kmax, dim3(1024), dim3(256), 0, stream, sc, mk);
  hipLaunchKernelGGL(kbuild, dim3(NPAD, BB), dim3(256), 0, stream, sc, M, mk);
  hipLaunchKernelGGL(kcopydiag, dim3(NSTEP * BB + BB), dim3(256), 0, stream,
                     M, Tpk0, D0, DA0, DB0, 0);
  for (int kb = 0; kb < 7; ++kb) {
    const int par = kb & 1;
    float* Dc = par ? D1 : D0;
    __bf16* DAc = par ? DA1 : DA0;
    __bf16* DBc = par ? DB1 : DB0;
    __bf16* Tc = par ? Tpk1 : Tpk0;
    __bf16* Tn = par ? Tpk0 : Tpk1;
    float* Dn = par ? D0 : D1;
    __bf16* DAn = par ? DA0 : DA1;
    __bf16* DBn = par ? DB0 : DB1;
    hipLaunchKernelGGL(kscale, dim3(NSTEP, BB), dim3(256), 0, stream, M, Dc, DAc, Rpk, kb);
    hipLaunchKernelGGL(kfused, dim3(16 + 128 + 784), dim3(256), 0, stream,
                       M, Tc, Tn, Rpk, DBc, Dn, DAn, DBn, kb);
  }
  hipLaunchKernelGGL(kscale, dim3(NSTEP, BB), dim3(256), 0, stream, M, D1, DA1, Rpk, 7);
  hipLaunchKernelGGL(kupdate, dim3(NSTEP, NSTEP - 1, BB), dim3(256), 0, stream,
                     M, Tpk1, Rpk, DB1, 7);
  hipLaunchKernelGGL(kfinal, dim3(16, 16, BB), dim3(256), 0, stream, sc, M, out, mk);
}